// Round 11
// baseline (148.720 us; speedup 1.0000x reference)
//
#include <hip/hip_runtime.h>

// JointLoss on MI355X. N=8192, D=256. Output: 1 fp32 scalar.
//
// ws layout (bytes):
//   [0,      32768)   pslots[2048][4] float: per-k_rows-block partials (cox,cnt,sim)
//   [32768,  294912)  gsum[2][8192][4] float (per matrix,row,group exp-sums)
//   [294912, +2M)     packed wsi fp8 e4m3 for MX K=128 MFMA:
//                     byte ((ks*4+q)*N + row)*32 + j holds emb[row][k],
//                     k = ks*128 + q*32 + j   (ks<2, q<4, j<32)
//   [294912+2M, +4M)  packed omic fp8 (same layout)
//
// R1: same-address atomics serialize -> spread/partial-write instead.
// R3/R7: unified VGPR+AGPR budget: over-ask waves -> spill (HBM scratch).
// R5: LDS-BW + exp-VALU bound -> fp8 (half bytes, same MFMA rate).
// R8/R9: spill fixed, 4 blk/CU; fp8 16x16x32 pipe-saturated at 54us.
// R10: MX K=128 verified; 45us = 14.4us MFMA (== MX floor) + 21us VALU
//      SUMMED (32%+47%): serial MFMA->epilogue dep chain phase-locks waves.
// Now: software-pipeline ct-loop (parity-double-buffered acc + B) so ct's
//      MFMAs overlap ct-1's exp epilogue -> target max(21,14.7)+stalls.

#define NN 8192
#define DD 256

typedef __attribute__((ext_vector_type(4))) float f32x4;
typedef __attribute__((ext_vector_type(4))) int i32x4;
typedef __attribute__((ext_vector_type(8))) int i32x8;

__device__ inline void gl_lds16(const void* g, void* l) {
  // async 16B/lane global->LDS; LDS dst must be wave-uniform base + lane*16
  __builtin_amdgcn_global_load_lds(
      (const __attribute__((address_space(1))) unsigned int*)g,
      (__attribute__((address_space(3))) unsigned int*)l, 16, 0, 0);
}

// ---------------------------------------------------------------------------
// K1 (fused): per-row everything. grid 2048 x 256 thr (4 waves, 1 row each).
//  - rank_i / at_risk_i by full O(N) scan per wave over LDS-staged chunks
//    (no atomics, no init): rank_i = #{j: t_j<t_i or (t_j==t_i and j<i)},
//    at_risk_i = sum over complement incl self of exp(clip(lr_j)).
//  - norms / cos-sim / Cox li -> NON-atomic per-block partial in pslots[blk].
//  - normalize -> fp8 -> scatter into rank-permuted MX-packed layout.
//  - first 64 blocks also zero gsum (runs before k_contrast in-stream).
// ---------------------------------------------------------------------------
__global__ void __launch_bounds__(256) k_rows(
    const float* __restrict__ lr, const float* __restrict__ times,
    const int* __restrict__ censor,
    const float* __restrict__ wsi, const float* __restrict__ omic,
    unsigned char* __restrict__ pw, unsigned char* __restrict__ po,
    float* __restrict__ pslots, float* __restrict__ gsum) {
  __shared__ __align__(16) float st[1024];
  __shared__ __align__(16) float se[1024];
  __shared__ float red[4][3];
  const int tid = threadIdx.x;
  const int lane = tid & 63;
  const int wv = tid >> 6;
  const int i = blockIdx.x * 4 + wv;

  if (blockIdx.x < 64) { // zero gsum (65536 floats) across first 64 blocks
    ((f32x4*)gsum)[blockIdx.x * 256 + tid] = (f32x4){0.f, 0.f, 0.f, 0.f};
  }

  // embeddings: norms + dot via wave shuffle
  const float4 w = ((const float4*)(wsi + (size_t)i * DD))[lane];
  const float4 o = ((const float4*)(omic + (size_t)i * DD))[lane];
  float nw = w.x * w.x + w.y * w.y + w.z * w.z + w.w * w.w;
  float no = o.x * o.x + o.y * o.y + o.z * o.z + o.w * o.w;
  float dd = w.x * o.x + w.y * o.y + w.z * o.z + w.w * o.w;
  for (int m = 1; m < 64; m <<= 1) {
    nw += __shfl_xor(nw, m);
    no += __shfl_xor(no, m);
    dd += __shfl_xor(dd, m);
  }
  const float nws = sqrtf(nw), nos = sqrtf(no);

  // rank + at_risk: scan all 8192 j in 8 LDS chunks of 1024
  const float ti = times[i];
  int rk = 0;
  float ar = 0.f;
  for (int c = 0; c < 8; ++c) {
    __syncthreads();
    for (int p = tid; p < 1024; p += 256) {
      float t = times[c * 1024 + p];
      float l = lr[c * 1024 + p];
      st[p] = t;
      se[p] = __expf(fminf(fmaxf(l, -10.f), 10.f));
    }
    __syncthreads();
#pragma unroll 4
    for (int jt = 0; jt < 16; ++jt) {
      const int p = jt * 64 + lane;
      const float t = st[p];
      const float e = se[p];
      const bool c1 = (t < ti) || ((t == ti) && ((c * 1024 + p) < i));
      rk += c1 ? 1 : 0;
      ar += c1 ? 0.f : e;
    }
  }
  for (int m = 1; m < 64; m <<= 1) {
    rk += __shfl_xor(rk, m);
    ar += __shfl_xor(ar, m);
  }

  if (lane == 0) {
    float c = dd / (fmaxf(nws, 1e-8f) * fmaxf(nos, 1e-8f));
    c = fminf(fmaxf(c, -1.f), 1.f);
    float l = fminf(fmaxf(lr[i], -10.f), 10.f);
    float li = l - logf(ar + 1e-15f);
    bool cen = (censor[i] == 1);
    red[wv][0] = cen ? li : 0.f;
    red[wv][1] = cen ? 1.f : 0.f;
    red[wv][2] = 1.f - c;
  }

  // normalize -> fp8 -> rank-permuted MX-packed scatter
  // lane covers k = lane*4..+3: ks=lane>>5, q=(lane>>3)&3, j=(lane&7)*4
  // -> offset ((ks*4+q)*NN + r)*32 + j.
  const int r = rk; // permuted row; r>>11 == risk group
  const float iw = 1.f / fmaxf(nws, 1e-12f);
  const float io = 1.f / fmaxf(nos, 1e-12f);
  int zw = __builtin_amdgcn_cvt_pk_fp8_f32(w.x * iw, w.y * iw, 0, false);
  zw = __builtin_amdgcn_cvt_pk_fp8_f32(w.z * iw, w.w * iw, zw, true);
  int zo = __builtin_amdgcn_cvt_pk_fp8_f32(o.x * io, o.y * io, 0, false);
  zo = __builtin_amdgcn_cvt_pk_fp8_f32(o.z * io, o.w * io, zo, true);
  const size_t off = ((size_t)((lane >> 5) * 4 + ((lane >> 3) & 3)) * NN + r) * 32
                     + (lane & 7) * 4;
  *(unsigned int*)(pw + off) = (unsigned int)zw;
  *(unsigned int*)(po + off) = (unsigned int)zo;
  __syncthreads();
  if (tid < 3) { // non-atomic per-block partial (every slot written -> no init)
    pslots[blockIdx.x * 4 + tid] =
        red[0][tid] + red[1][tid] + red[2][tid] + red[3][tid];
  }
}

// ---------------------------------------------------------------------------
// K2: contrastive exp-sums, MX fp8 K=128, software-pipelined epilogue.
// grid (16 cb, 64 rb, 2 mz) x 256 thr, launch_bounds(256,4) -> 128-reg
// budget, 4 blocks/CU. Block = 128 rows x 512 cols (8 stages x 64 cols).
// Wave owns 32 rows: afrag[2 rt][2 ks] i32x8 = 32 regs resident.
// B double-buffered LDS 2 x 16 KB via global_load_lds.
//
// ct-loop is parity-double-buffered (acc[2], bfr[2]): ct's MFMAs are issued
// before ct-1's exp epilogue VALU runs -> matrix pipe and VALU overlap
// within the wave (R10 showed them summing, 32%+47%).
//
// MX operand layout: lane(q,lo) holds 32 B = X[lo][k = ks*128+q*32..+31];
// unit scale 0x7F. LDS: region(ct,ks,h) = ((ct*2+ks)*2+h)*1024; lane l holds
// 16 B (k-half h) at region + l*16 -> lane-linear ds_read_b128, conflict-
// free. DMA chunk u=(wv*4+p)*64+lane writes byte u*16; decode ct=u>>8,
// ks=(u>>7)&1, h=(u>>6)&1, l=u&63 -> src pk+((ks*4+(l>>4))*NN+col)*32+h*16,
// col = colstart+ct*16+(l&15). Group g = cb>>2 const per block. Diagonal:
// wave rows are the (wv&1)-half of a 64-col window.
// ---------------------------------------------------------------------------
__device__ inline void epi(const f32x4& a0, const f32x4& a1, int ct,
                           bool diagw, int dctbase, int lo, int q,
                           float s[2][4]) {
  if (diagw) {
#pragma unroll
    for (int r = 0; r < 4; ++r) {
      float e0 = __builtin_amdgcn_exp2f(fmaf(a0[r], 14.4269504f, -14.4269504f));
      float e1 = __builtin_amdgcn_exp2f(fmaf(a1[r], 14.4269504f, -14.4269504f));
      if (ct == dctbase + 0 && lo == q * 4 + r) e0 = 0.f; // exact diagonal
      if (ct == dctbase + 1 && lo == q * 4 + r) e1 = 0.f;
      s[0][r] += e0;
      s[1][r] += e1;
    }
  } else {
#pragma unroll
    for (int r = 0; r < 4; ++r) {
      s[0][r] += __builtin_amdgcn_exp2f(fmaf(a0[r], 14.4269504f, -14.4269504f));
      s[1][r] += __builtin_amdgcn_exp2f(fmaf(a1[r], 14.4269504f, -14.4269504f));
    }
  }
}

__global__ void __launch_bounds__(256, 4) k_contrast(
    const unsigned char* __restrict__ pw, const unsigned char* __restrict__ po,
    float* __restrict__ gsum) {
  __shared__ __align__(16) unsigned char sbuf[2][16384]; // 2 x 16 KB
  const int tid = threadIdx.x;
  const int lane = tid & 63;
  const int wv = tid >> 6;                 // 0..3
  const int lo = lane & 15, q = lane >> 4; // MFMA frag coords
  const int cb = blockIdx.x, rb = blockIdx.y, mz = blockIdx.z;
  const unsigned char* __restrict__ pk = (mz == 0) ? pw : po;
  const int rowbase = rb * 128 + wv * 32;
  const int colstart = cb * 512;
  const int g = cb >> 2;

  // A fragments: 2 row-tiles x 2 K-segments x 32 B = 32 regs, resident
  i32x8 afrag[2][2];
#pragma unroll
  for (int rt = 0; rt < 2; ++rt) {
    const size_t row = rowbase + rt * 16 + lo;
#pragma unroll
    for (int ks = 0; ks < 2; ++ks)
      afrag[rt][ks] = *(const i32x8*)(pk + ((size_t)(ks * 4 + q) * NN + row) * 32);
  }

  // per-lane DMA sources, 4 chunks/wave (advance +2048 B per stage = +64 cols)
  const unsigned char* gsrc[4];
#pragma unroll
  for (int p = 0; p < 4; ++p) {
    const int u = (wv * 4 + p) * 64 + lane;
    const int uct = u >> 8, uks = (u >> 7) & 1, uh = (u >> 6) & 1;
    const int ul = u & 63;
    gsrc[p] = pk + ((size_t)(uks * 4 + (ul >> 4)) * NN
                    + colstart + uct * 16 + (ul & 15)) * 32 + uh * 16;
  }
  unsigned char* const ldb = &sbuf[0][(size_t)wv * 4096];

#pragma unroll
  for (int p = 0; p < 4; ++p) gl_lds16(gsrc[p], ldb + p * 1024);
  __syncthreads();

  float s[2][4] = {{0.f}};
  const int dctbase = (wv & 1) * 2; // wave's 32 rows within the 64-col window
  const int lbase = lane * 16;

#pragma unroll 1
  for (int st = 0; st < 8; ++st) {
    if (st < 7) { // async-prefetch next stage into other buffer
      const size_t adv = (size_t)(st + 1) * 2048;
      const size_t bofs = ((st + 1) & 1) ? 16384 : 0;
#pragma unroll
      for (int p = 0; p < 4; ++p) gl_lds16(gsrc[p] + adv, ldb + bofs + p * 1024);
    }
    const unsigned char* buf = &sbuf[st & 1][0];
    const bool diagw = ((rowbase >> 6) == ((colstart + st * 64) >> 6));

    i32x8 bfr[2][2]; // [parity][ks]
    f32x4 acc0[2], acc1[2];
    // preload B for ct=0
#pragma unroll
    for (int ks = 0; ks < 2; ++ks) {
      const int rbase = (ks * 2) * 1024 + lbase;
      i32x4 blo = *(const i32x4*)&buf[rbase];
      i32x4 bhi = *(const i32x4*)&buf[rbase + 1024];
      bfr[0][ks] = __builtin_shufflevector(blo, bhi, 0, 1, 2, 3, 4, 5, 6, 7);
    }
#pragma unroll
    for (int ct = 0; ct < 4; ++ct) {
      const int cur = ct & 1, oth = cur ^ 1;
      // issue MFMAs for ct first (matrix pipe)
      f32x4 z = {0.f, 0.f, 0.f, 0.f};
      acc0[cur] = z; acc1[cur] = z;
#pragma unroll
      for (int ks = 0; ks < 2; ++ks) {
        acc0[cur] = __builtin_amdgcn_mfma_scale_f32_16x16x128_f8f6f4(
            afrag[0][ks], bfr[cur][ks], acc0[cur], 0, 0, 0, 0x7F, 0, 0x7F);
        acc1[cur] = __builtin_amdgcn_mfma_scale_f32_16x16x128_f8f6f4(
            afrag[1][ks], bfr[cur][ks], acc1[cur], 0, 0, 0, 0x7F, 0, 0x7F);
      }
      // prefetch B for ct+1 (LDS pipe, overlaps MFMAs)
      if (ct < 3) {
#pragma unroll
        for (int ks = 0; ks < 2; ++ks) {
          const int rbase = (((ct + 1) * 2 + ks) * 2) * 1024 + lbase;
          i32x4 blo = *(const i32x4*)&buf[rbase];
          i32x4 bhi = *(const i32x4*)&buf[rbase + 1024];
          bfr[oth][ks] = __builtin_shufflevector(blo, bhi, 0, 1, 2, 3, 4, 5, 6, 7);
        }
      }
      // epilogue for ct-1 (VALU, overlaps ct's in-flight MFMAs)
      if (ct > 0) epi(acc0[oth], acc1[oth], ct - 1, diagw, dctbase, lo, q, s);
    }
    epi(acc0[1], acc1[1], 3, diagw, dctbase, lo, q, s);
    __syncthreads();
  }

  // flush: reduce over 16 col-lanes, one atomic per (row, group)
#pragma unroll
  for (int rt = 0; rt < 2; ++rt)
#pragma unroll
    for (int r = 0; r < 4; ++r) {
      float v = s[rt][r];
      v += __shfl_xor(v, 1); v += __shfl_xor(v, 2);
      v += __shfl_xor(v, 4); v += __shfl_xor(v, 8);
      if (lo == 0) {
        const int row = rowbase + rt * 16 + q * 4 + r; // C/D: row=(lane>>4)*4+reg
        atomicAdd(&gsum[((size_t)mz * NN + row) * 4 + g], v);
      }
    }
}

// ---------------------------------------------------------------------------
// K3: finale. One block, 1024 thr. Reduces pslots (cox,cnt,sim), computes
// per-row LSE differences from gsum, combines the scalar.
// ---------------------------------------------------------------------------
__global__ void __launch_bounds__(1024) k_finale(
    const float* __restrict__ pslots, const float* __restrict__ gsum,
    float* __restrict__ out) {
  __shared__ float rsum[16][4];
  const int tid = threadIdx.x;
  const int lane = tid & 63, wv = tid >> 6;
  float cox = 0.f, cnt = 0.f, sim = 0.f, con = 0.f;
  for (int b = tid; b < 2048; b += 1024) {
    const float4 v = ((const float4*)pslots)[b];
    cox += v.x; cnt += v.y; sim += v.z;
  }
  for (int idx = tid; idx < 2 * NN; idx += 1024) {
    const float4 v = ((const float4*)gsum)[idx];
    const int row = idx & (NN - 1);
    const int gg = row >> 11; // group of permuted row
    const float sg = (gg == 0) ? v.x : (gg == 1) ? v.y : (gg == 2) ? v.z : v.w;
    con += logf(v.x + v.y + v.z + v.w) - logf(sg); // fixed shifts cancel
  }
  for (int m = 1; m < 64; m <<= 1) {
    cox += __shfl_xor(cox, m);
    cnt += __shfl_xor(cnt, m);
    sim += __shfl_xor(sim, m);
    con += __shfl_xor(con, m);
  }
  if (lane == 0) {
    rsum[wv][0] = cox; rsum[wv][1] = cnt; rsum[wv][2] = sim; rsum[wv][3] = con;
  }
  __syncthreads();
  if (tid == 0) {
    float c0 = 0.f, c1 = 0.f, c2 = 0.f, c3 = 0.f;
    for (int k = 0; k < 16; ++k) {
      c0 += rsum[k][0]; c1 += rsum[k][1]; c2 += rsum[k][2]; c3 += rsum[k][3];
    }
    out[0] = -c0 / fmaxf(c1, 1.f) + c2 / (float)NN
             + 0.1f * 0.5f * c3 / (float)NN;
  }
}

extern "C" void kernel_launch(void* const* d_in, const int* in_sizes, int n_in,
                              void* d_out, int out_size, void* d_ws, size_t ws_size,
                              hipStream_t stream) {
  const float* lr = (const float*)d_in[0];
  const float* times = (const float*)d_in[1];
  const int* censor = (const int*)d_in[2];
  const float* wsi = (const float*)d_in[3];
  const float* omic = (const float*)d_in[4];
  float* out = (float*)d_out;

  char* ws = (char*)d_ws;
  float* pslots = (float*)ws;
  float* gsum = (float*)(ws + 32768);
  unsigned char* pw = (unsigned char*)(ws + 294912);
  unsigned char* po = (unsigned char*)(ws + 294912 + 2097152);

  k_rows<<<2048, 256, 0, stream>>>(lr, times, censor, wsi, omic, pw, po, pslots, gsum);
  k_contrast<<<dim3(16, 64, 2), 256, 0, stream>>>(pw, po, gsum);
  k_finale<<<1, 1024, 0, stream>>>(pslots, gsum, out);
}